// Round 10
// baseline (312.769 us; speedup 1.0000x reference)
//
#include <hip/hip_runtime.h>
#include <math.h>

#define N_NODES 8192
#define N_FEAT  256
#define N_EDGES 131072
#define N_DIR   (2*N_EDGES)
#define MAXDEG  128    // in-degree is Poisson(32); P(>=128) ~ 0 (16 sigma)
#define ACT_CAP 24576  // LDS capacity for residual active pairs

typedef unsigned int u32x4 __attribute__((ext_vector_type(4)));

// ---------- helpers ----------

// directed edge k: s = ei[k]; d = ei[k<E ? k+E : k-E]
__device__ __forceinline__ void edge_sd(const int* __restrict__ ei, int k, int& s, int& d){
  s = ei[k];
  d = (k < N_EDGES) ? ei[k + N_EDGES] : ei[k - N_EDGES];
}

// ---------- kernels ----------

// init meta (cnt|deg|np|ngact -> 0) and global label array
__global__ void k_start(int* __restrict__ meta, int nmeta, int* __restrict__ Lg){
  int i = blockIdx.x * blockDim.x + threadIdx.x;
  if (i < nmeta) meta[i] = 0;
  if (i < N_NODES) Lg[i] = i;
}

// p1[i] = dot(x[i], w[:256]); p2[i] = dot(x[i], w[256:])  (f64 accumulate)
__global__ void k_proj(const float* __restrict__ x, const float* __restrict__ w,
                       float* __restrict__ p1, float* __restrict__ p2){
  int i = blockIdx.x;
  int t = threadIdx.x;                  // 256 threads
  float v = x[(size_t)i * N_FEAT + t];
  double a = (double)v * (double)w[t];
  double b = (double)v * (double)w[N_FEAT + t];
  for (int off = 32; off; off >>= 1){
    a += __shfl_down(a, off);
    b += __shfl_down(b, off);
  }
  __shared__ double sa[4], sb[4];
  int wid = t >> 6, lane = t & 63;
  if (lane == 0){ sa[wid] = a; sb[wid] = b; }
  __syncthreads();
  if (t == 0){
    p1[i] = (float)(sa[0] + sa[1] + sa[2] + sa[3]);
    p2[i] = (float)(sb[0] + sb[1] + sb[2] + sb[3]);
  }
}

// e per directed edge; (src,e) slot record by destination; contract degree;
// wave-aggregated compaction of contract pairs.
__global__ void k_edges(const int* __restrict__ ei, const float* __restrict__ p1,
                        const float* __restrict__ p2, const float* __restrict__ lb,
                        int* __restrict__ cnt, int* __restrict__ deg,
                        uint2* __restrict__ edata,
                        unsigned int* __restrict__ pairs, int* __restrict__ np){
  int k = blockIdx.x * blockDim.x + threadIdx.x;
  int s, d; edge_sd(ei, k, s, d);
  bool selfe = (s == d);
  float e = 0.0f;
  if (!selfe){
    float z = p1[s] + p2[d] + lb[0];
    e = tanhf(z);
    int slot = atomicAdd(&cnt[d], 1);
    uint2 v; v.x = (unsigned int)s; v.y = __float_as_uint(e);
    edata[(size_t)d * MAXDEG + slot] = v;
    if (e > 0.0f){
      atomicAdd(&deg[s], 1);
      atomicAdd(&deg[d], 1);
    }
  }
  bool c = (!selfe) && (e > 0.0f);
  unsigned long long m = __ballot(c);
  if (m){
    int lane = threadIdx.x & 63;
    int leader = __ffsll((unsigned long long)m) - 1;
    int base = 0;
    if (lane == leader) base = atomicAdd(np, __popcll(m));
    base = __shfl(base, leader);
    if (c){
      int prefix = __popcll(m & ((1ull << lane) - 1ull));
      pairs[base + prefix] = ((unsigned int)s << 13) | (unsigned int)d;
    }
  }
}

// parallel relax pass: fire-and-forget device-scope atomicMin (no chains).
// Every lowering also hooks the old parent -> flatten propagates minima.
__global__ void k_relax(const unsigned int* __restrict__ pairs,
                        const int* __restrict__ np, int* __restrict__ Lg){
  int n = *np;
  int k = blockIdx.x * blockDim.x + threadIdx.x;
  int stride = gridDim.x * blockDim.x;
  for (; k < n; k += stride){
    unsigned int p = pairs[k];
    int s = (int)(p >> 13), d = (int)(p & 8191u);
    int a = Lg[s], b = Lg[d];
    if (a == b) continue;
    int m = a < b ? a : b;
    atomicMin(&Lg[s], m);
    atomicMin(&Lg[d], m);
    if (a > m) atomicMin(&Lg[a], m);    // hook s's old parent
    else       atomicMin(&Lg[b], m);    // hook d's old parent
  }
}

// parallel flatten: pointer-jump every node to its root (chains are static
// across this dispatch; shortcut writes are benign).
__global__ void k_flat(int* __restrict__ Lg){
  int i = blockIdx.x * blockDim.x + threadIdx.x;
  if (i >= N_NODES) return;
  int l = Lg[i];
  while (true){ int q = Lg[l]; if (q == l) break; l = q; }
  Lg[i] = l;
}

// compact still-active pairs (distinct roots) -> gact (quiescent labels)
__global__ void k_collect(const unsigned int* __restrict__ pairs,
                          const int* __restrict__ np, const int* __restrict__ Lg,
                          unsigned int* __restrict__ gact, int* __restrict__ ngact){
  int n = *np;
  int k = blockIdx.x * blockDim.x + threadIdx.x;
  int stride = gridDim.x * blockDim.x;
  for (; k < n; k += stride){
    unsigned int p = pairs[k];
    int s = (int)(p >> 13), d = (int)(p & 8191u);
    bool act = (Lg[s] != Lg[d]);
    unsigned long long m = __ballot(act);
    if (m){
      int lane = threadIdx.x & 63;
      int leader = __ffsll((unsigned long long)m) - 1;
      int base = 0;
      if (lane == leader) base = atomicAdd(ngact, __popcll(m));
      base = __shfl(base, leader);
      if (act){
        int prefix = __popcll(m & ((1ull << lane) - 1ull));
        gact[base + prefix] = p;
      }
    }
  }
}

// FUSED: block 0 = exact CC fixpoint on residual actives (LDS) + rank + emit;
// blocks 1.. = nontemporal-zero X_new and A_c.
__global__ void __launch_bounds__(1024) k_fused(
    const unsigned int* __restrict__ gact, const int* __restrict__ ngact,
    const int* __restrict__ Lg, const int* __restrict__ batch,
    int* __restrict__ cluster_i, float* __restrict__ out_cluster,
    float* __restrict__ out_batch,
    u32x4* __restrict__ zbase, long long n4){
  int t = threadIdx.x;

  if (blockIdx.x != 0){
    long long i = (long long)(blockIdx.x - 1) * blockDim.x + t;
    long long stride = (long long)(gridDim.x - 1) * blockDim.x;
    u32x4 z = (u32x4)(0u);
    for (; i < n4; i += stride) __builtin_nontemporal_store(z, &zbase[i]);
    return;
  }

  // ---- block 0 ----
  __shared__ int L[N_NODES];            // 32 KB (flattened labels)
  __shared__ int wsum[1024];            // 4 KB scan buffer
  __shared__ unsigned int act[ACT_CAP]; // 96 KB residual pairs
  __shared__ int flag;

  for (int i = t; i < N_NODES; i += 1024) L[i] = Lg[i];
  for (int i = t; i < N_NODES; i += 1024) out_batch[i] = 0.0f;
  __syncthreads();

  int na = *ngact;
  if (na > 0){
    bool inlds = (na <= ACT_CAP);
    if (inlds){
      for (int k = t; k < na; k += 1024) act[k] = gact[k];
    }
    __syncthreads();
    while (true){
      if (t == 0) flag = 0;
      __syncthreads();
      for (int k = t; k < na; k += 1024){
        unsigned int p = inlds ? act[k] : gact[k];
        int s = (int)(p >> 13), d = (int)(p & 8191u);
        int a = L[s], b = L[d];
        if (a == b) continue;
        int m = a < b ? a : b;
        atomicMin(&L[s], m);
        atomicMin(&L[d], m);
        if (a > m) atomicMin(&L[a], m);
        else       atomicMin(&L[b], m);
        flag = 1;
      }
      __syncthreads();
      if (!flag) break;
      for (int i = t; i < N_NODES; i += 1024){
        int l = L[i];
        while (true){ int q = L[l]; if (q == l) break; l = q; }
        L[i] = l;
      }
      __syncthreads();
    }
  }

  // L[i] == min node index of i's component (flattened)
  int base = t * 8;
  int l_reg[8];
  #pragma unroll
  for (int j = 0; j < 8; ++j) l_reg[j] = L[base + j];
  __syncthreads();

  // rank roots: flag + block-wide scan (1024 threads x 8)
  int f[8]; int s = 0;
  #pragma unroll
  for (int j = 0; j < 8; ++j){ f[j] = (l_reg[j] == base + j) ? 1 : 0; s += f[j]; }
  wsum[t] = s;
  __syncthreads();
  for (int off = 1; off < 1024; off <<= 1){
    int v = (t >= off) ? wsum[t - off] : 0;
    __syncthreads();
    wsum[t] += v;
    __syncthreads();
  }
  int run = wsum[t] - s;                // exclusive prefix
  #pragma unroll
  for (int j = 0; j < 8; ++j){
    run += f[j];
    if (f[j]) L[base + j] = run - 1;    // root slot <- cluster id
  }
  __syncthreads();

  #pragma unroll
  for (int j = 0; j < 8; ++j){
    int i = base + j;
    int c = L[l_reg[j]];
    cluster_i[i] = c;
    out_cluster[i] = (float)c;
    out_batch[c] = (float)batch[i];     // last-write-wins; batch uniform (0)
  }
}

// y[i,:] = (isolated ? x[i,:] : 0) + sum_{edges s->i} e * x[s,:]
__global__ void k_y(const float* __restrict__ x, const uint2* __restrict__ edata,
                    const int* __restrict__ cnt, const int* __restrict__ deg,
                    float* __restrict__ y){
  int i = blockIdx.x;
  int t = threadIdx.x;                  // 256 threads = feature dim
  int m = cnt[i];
  float acc = (deg[i] == 0) ? x[(size_t)i * N_FEAT + t] : 0.0f;
  const uint2* row = edata + (size_t)i * MAXDEG;
  for (int j = 0; j < m; ++j){
    uint2 v = row[j];
    acc += __uint_as_float(v.y) * x[(size_t)v.x * N_FEAT + t];
  }
  y[(size_t)i * N_FEAT + t] = acc;
}

// X_new[cluster[i],:] += y[i,:]  (run-length register accumulation, then atomicAdd)
__global__ void k_xnew(const float* __restrict__ y, const int* __restrict__ cluster_i,
                       float* __restrict__ Xn){
  int t = threadIdx.x;                  // 256 threads
  int node0 = blockIdx.x * 32;
  float acc = 0.0f;
  int cur = cluster_i[node0];
  for (int j = 0; j < 32; ++j){
    int node = node0 + j;
    int c = cluster_i[node];
    if (c != cur){
      atomicAdd(&Xn[(size_t)cur * N_FEAT + t], acc);
      acc = 0.0f; cur = c;
    }
    acc += y[(size_t)node * N_FEAT + t];
  }
  atomicAdd(&Xn[(size_t)cur * N_FEAT + t], acc);
}

// A_c[cs,cd] += 1 per directed non-self edge crossing clusters (diag zeroed by ref)
__global__ void k_ac(const int* __restrict__ ei, const int* __restrict__ cluster_i,
                     float* __restrict__ Ac){
  int k = blockIdx.x * blockDim.x + threadIdx.x;
  if (k >= N_DIR) return;
  int s, d; edge_sd(ei, k, s, d);
  if (s == d) return;
  int cs = cluster_i[s], cd = cluster_i[d];
  if (cs != cd) atomicAdd(&Ac[(size_t)cs * N_NODES + cd], 1.0f);
}

// ---------- launcher ----------

extern "C" void kernel_launch(void* const* d_in, const int* in_sizes, int n_in,
                              void* d_out, int out_size, void* d_ws, size_t ws_size,
                              hipStream_t stream){
  const float* x     = (const float*)d_in[0];
  const int*   ei    = (const int*)  d_in[1];
  const int*   batch = (const int*)  d_in[2];
  const float* lw    = (const float*)d_in[3];
  const float* lb    = (const float*)d_in[4];

  float* out = (float*)d_out;
  float* Xn  = out;                                       // 8192*256
  float* Ac  = Xn + (size_t)N_NODES * N_FEAT;             // 8192*8192
  float* ob  = Ac + (size_t)N_NODES * N_NODES;            // 8192 (new_batch)
  float* oc  = ob + N_NODES;                              // 8192 (cluster)

  char* w = (char*)d_ws;
  float* p1        = (float*)w; w += (size_t)N_NODES * 4;
  float* p2        = (float*)w; w += (size_t)N_NODES * 4;
  int*   cluster_i = (int*)  w; w += (size_t)N_NODES * 4;
  int*   Lg        = (int*)  w; w += (size_t)N_NODES * 4;
  // contiguous meta block: cnt | deg | np | ngact  (zeroed by k_start)
  int*   meta      = (int*)  w;
  int*   cnt       = meta;
  int*   deg       = meta + N_NODES;
  int*   np        = meta + 2 * N_NODES;
  int*   ngact     = meta + 2 * N_NODES + 1;
  int    nmeta     = 2 * N_NODES + 16;
  w += (size_t)nmeta * 4;
  unsigned int* pairs = (unsigned int*)w; w += (size_t)N_DIR * 4;
  unsigned int* gact  = (unsigned int*)w; w += (size_t)N_DIR * 4;
  uint2* edata     = (uint2*)w; w += (size_t)N_NODES * MAXDEG * 8;
  float* y         = (float*)w; w += (size_t)N_NODES * N_FEAT * 4;

  // Xn + Ac region (ob/oc handled by fused block 0)
  long long n4 = ((long long)N_NODES * N_FEAT + (long long)N_NODES * N_NODES) / 4;

  k_start  <<<(nmeta + 255) / 256, 256, 0, stream>>>(meta, nmeta, Lg);
  k_proj   <<<N_NODES, 256, 0, stream>>>(x, lw, p1, p2);
  k_edges  <<<N_DIR / 256, 256, 0, stream>>>(ei, p1, p2, lb, cnt, deg, edata, pairs, np);
  k_relax  <<<512, 256, 0, stream>>>(pairs, np, Lg);
  k_flat   <<<N_NODES / 256, 256, 0, stream>>>(Lg);
  k_relax  <<<512, 256, 0, stream>>>(pairs, np, Lg);
  k_flat   <<<N_NODES / 256, 256, 0, stream>>>(Lg);
  k_collect<<<512, 256, 0, stream>>>(pairs, np, Lg, gact, ngact);
  k_fused  <<<256, 1024, 0, stream>>>(gact, ngact, Lg, batch, cluster_i, oc, ob,
                                      (u32x4*)out, n4);
  k_y      <<<N_NODES, 256, 0, stream>>>(x, edata, cnt, deg, y);
  k_xnew   <<<N_NODES / 32, 256, 0, stream>>>(y, cluster_i, Xn);
  k_ac     <<<N_DIR / 256, 256, 0, stream>>>(ei, cluster_i, Ac);
}

// Round 11
// 250.138 us; speedup vs baseline: 1.2504x; 1.2504x over previous
//
#include <hip/hip_runtime.h>
#include <math.h>

#define N_NODES 8192
#define N_FEAT  256
#define N_EDGES 131072
#define N_DIR   (2*N_EDGES)
#define MAXDEG  128    // in-degree is Poisson(32); P(>=128) ~ 0 (16 sigma)
#define ACT_CAP 24576  // LDS capacity for residual active pairs

typedef unsigned int u32x4 __attribute__((ext_vector_type(4)));

// ---------- helpers ----------

// directed edge k: s = ei[k]; d = ei[k<E ? k+E : k-E]
__device__ __forceinline__ void edge_sd(const int* __restrict__ ei, int k, int& s, int& d){
  s = ei[k];
  d = (k < N_EDGES) ? ei[k + N_EDGES] : ei[k - N_EDGES];
}

// ---------- kernels ----------

// init meta (cnt|deg|np|ngact -> 0) and global label array
__global__ void k_start(int* __restrict__ meta, int nmeta, int* __restrict__ Lg){
  int i = blockIdx.x * blockDim.x + threadIdx.x;
  if (i < nmeta) meta[i] = 0;
  if (i < N_NODES) Lg[i] = i;
}

// p1[i] = dot(x[i], w[:256]); p2[i] = dot(x[i], w[256:])  (f64 accumulate)
__global__ void k_proj(const float* __restrict__ x, const float* __restrict__ w,
                       float* __restrict__ p1, float* __restrict__ p2){
  int i = blockIdx.x;
  int t = threadIdx.x;                  // 256 threads
  float v = x[(size_t)i * N_FEAT + t];
  double a = (double)v * (double)w[t];
  double b = (double)v * (double)w[N_FEAT + t];
  for (int off = 32; off; off >>= 1){
    a += __shfl_down(a, off);
    b += __shfl_down(b, off);
  }
  __shared__ double sa[4], sb[4];
  int wid = t >> 6, lane = t & 63;
  if (lane == 0){ sa[wid] = a; sb[wid] = b; }
  __syncthreads();
  if (t == 0){
    p1[i] = (float)(sa[0] + sa[1] + sa[2] + sa[3]);
    p2[i] = (float)(sb[0] + sb[1] + sb[2] + sb[3]);
  }
}

// e per directed edge; (src,e) slot record by destination; contract degree;
// wave-aggregated compaction of contract pairs.
__global__ void k_edges(const int* __restrict__ ei, const float* __restrict__ p1,
                        const float* __restrict__ p2, const float* __restrict__ lb,
                        int* __restrict__ cnt, int* __restrict__ deg,
                        uint2* __restrict__ edata,
                        unsigned int* __restrict__ pairs, int* __restrict__ np){
  int k = blockIdx.x * blockDim.x + threadIdx.x;
  int s, d; edge_sd(ei, k, s, d);
  bool selfe = (s == d);
  float e = 0.0f;
  if (!selfe){
    float z = p1[s] + p2[d] + lb[0];
    e = tanhf(z);
    int slot = atomicAdd(&cnt[d], 1);
    uint2 v; v.x = (unsigned int)s; v.y = __float_as_uint(e);
    edata[(size_t)d * MAXDEG + slot] = v;
    if (e > 0.0f){
      atomicAdd(&deg[s], 1);
      atomicAdd(&deg[d], 1);
    }
  }
  bool c = (!selfe) && (e > 0.0f);
  unsigned long long m = __ballot(c);
  if (m){
    int lane = threadIdx.x & 63;
    int leader = __ffsll((unsigned long long)m) - 1;
    int base = 0;
    if (lane == leader) base = atomicAdd(np, __popcll(m));
    base = __shfl(base, leader);
    if (c){
      int prefix = __popcll(m & ((1ull << lane) - 1ull));
      pairs[base + prefix] = ((unsigned int)s << 13) | (unsigned int)d;
    }
  }
}

// pure edge relaxation: ONE guarded atomicMin on the larger endpoint only.
// Addresses (s,d) are uniform over the node range -> no hot cache lines.
__global__ void k_relax(const unsigned int* __restrict__ pairs,
                        const int* __restrict__ np, int* __restrict__ Lg){
  int n = *np;
  int k = blockIdx.x * blockDim.x + threadIdx.x;
  int stride = gridDim.x * blockDim.x;
  for (; k < n; k += stride){
    unsigned int p = pairs[k];
    int s = (int)(p >> 13), d = (int)(p & 8191u);
    int a = Lg[s], b = Lg[d];
    if (a < b)      atomicMin(&Lg[d], a);
    else if (b < a) atomicMin(&Lg[s], b);
  }
}

// flatten: pointer-jump every node to its label fixpoint (labels are node
// indices, strictly decreasing along chains -> terminates; shortcuts benign).
__global__ void k_flat(int* __restrict__ Lg){
  int i = blockIdx.x * blockDim.x + threadIdx.x;
  if (i >= N_NODES) return;
  int l = Lg[i];
  while (true){ int q = Lg[l]; if (q == l) break; l = q; }
  Lg[i] = l;
}

// compact still-active pairs (distinct labels) on the quiescent post-flatten
// state. Pairs with equal labels are provably intra-component (label is a
// member of both endpoints' components) -> safe to drop.
__global__ void k_collect(const unsigned int* __restrict__ pairs,
                          const int* __restrict__ np, const int* __restrict__ Lg,
                          unsigned int* __restrict__ gact, int* __restrict__ ngact){
  int n = *np;
  int k = blockIdx.x * blockDim.x + threadIdx.x;
  int stride = gridDim.x * blockDim.x;
  for (; k < n; k += stride){
    unsigned int p = pairs[k];
    int s = (int)(p >> 13), d = (int)(p & 8191u);
    bool act = (Lg[s] != Lg[d]);
    unsigned long long m = __ballot(act);
    if (m){
      int lane = threadIdx.x & 63;
      int leader = __ffsll((unsigned long long)m) - 1;
      int base = 0;
      if (lane == leader) base = atomicAdd(ngact, __popcll(m));
      base = __shfl(base, leader);
      if (act){
        int prefix = __popcll(m & ((1ull << lane) - 1ull));
        gact[base + prefix] = p;
      }
    }
  }
}

// FUSED: block 0 = exact CC fixpoint on residual actives (LDS) + rank + emit;
// blocks 1.. = nontemporal-zero X_new and A_c.
__global__ void __launch_bounds__(1024) k_fused(
    const unsigned int* __restrict__ gact, const int* __restrict__ ngact,
    const int* __restrict__ Lg, const int* __restrict__ batch,
    int* __restrict__ cluster_i, float* __restrict__ out_cluster,
    float* __restrict__ out_batch,
    u32x4* __restrict__ zbase, long long n4){
  int t = threadIdx.x;

  if (blockIdx.x != 0){
    long long i = (long long)(blockIdx.x - 1) * blockDim.x + t;
    long long stride = (long long)(gridDim.x - 1) * blockDim.x;
    u32x4 z = (u32x4)(0u);
    for (; i < n4; i += stride) __builtin_nontemporal_store(z, &zbase[i]);
    return;
  }

  // ---- block 0 ----
  __shared__ int L[N_NODES];            // 32 KB (labels)
  __shared__ int wsum[1024];            // 4 KB scan buffer
  __shared__ unsigned int act[ACT_CAP]; // 96 KB residual pairs
  __shared__ int flag;

  for (int i = t; i < N_NODES; i += 1024) L[i] = Lg[i];
  for (int i = t; i < N_NODES; i += 1024) out_batch[i] = 0.0f;
  __syncthreads();

  int na = *ngact;
  if (na > 0){
    bool inlds = (na <= ACT_CAP);
    if (inlds){
      for (int k = t; k < na; k += 1024) act[k] = gact[k];
    }
    __syncthreads();
    while (true){
      if (t == 0) flag = 0;
      __syncthreads();
      for (int k = t; k < na; k += 1024){
        unsigned int p = inlds ? act[k] : gact[k];
        int s = (int)(p >> 13), d = (int)(p & 8191u);
        int a = L[s], b = L[d];
        if (a == b) continue;
        int m = a < b ? a : b;
        atomicMin(&L[s], m);
        atomicMin(&L[d], m);
        if (a > m) atomicMin(&L[a], m);
        else       atomicMin(&L[b], m);
        flag = 1;
      }
      __syncthreads();
      if (!flag) break;
      for (int i = t; i < N_NODES; i += 1024){
        int l = L[i];
        while (true){ int q = L[l]; if (q == l) break; l = q; }
        L[i] = l;
      }
      __syncthreads();
    }
  }

  // L[i] == min node index of i's component (flattened)
  int base = t * 8;
  int l_reg[8];
  #pragma unroll
  for (int j = 0; j < 8; ++j) l_reg[j] = L[base + j];
  __syncthreads();

  // rank roots: flag + block-wide scan (1024 threads x 8)
  int f[8]; int s = 0;
  #pragma unroll
  for (int j = 0; j < 8; ++j){ f[j] = (l_reg[j] == base + j) ? 1 : 0; s += f[j]; }
  wsum[t] = s;
  __syncthreads();
  for (int off = 1; off < 1024; off <<= 1){
    int v = (t >= off) ? wsum[t - off] : 0;
    __syncthreads();
    wsum[t] += v;
    __syncthreads();
  }
  int run = wsum[t] - s;                // exclusive prefix
  #pragma unroll
  for (int j = 0; j < 8; ++j){
    run += f[j];
    if (f[j]) L[base + j] = run - 1;    // root slot <- cluster id
  }
  __syncthreads();

  #pragma unroll
  for (int j = 0; j < 8; ++j){
    int i = base + j;
    int c = L[l_reg[j]];
    cluster_i[i] = c;
    out_cluster[i] = (float)c;
    out_batch[c] = (float)batch[i];     // last-write-wins; batch uniform (0)
  }
}

// y[i,:] = (isolated ? x[i,:] : 0) + sum_{edges s->i} e * x[s,:]
__global__ void k_y(const float* __restrict__ x, const uint2* __restrict__ edata,
                    const int* __restrict__ cnt, const int* __restrict__ deg,
                    float* __restrict__ y){
  int i = blockIdx.x;
  int t = threadIdx.x;                  // 256 threads = feature dim
  int m = cnt[i];
  float acc = (deg[i] == 0) ? x[(size_t)i * N_FEAT + t] : 0.0f;
  const uint2* row = edata + (size_t)i * MAXDEG;
  for (int j = 0; j < m; ++j){
    uint2 v = row[j];
    acc += __uint_as_float(v.y) * x[(size_t)v.x * N_FEAT + t];
  }
  y[(size_t)i * N_FEAT + t] = acc;
}

// X_new[cluster[i],:] += y[i,:]  (run-length register accumulation, then atomicAdd)
__global__ void k_xnew(const float* __restrict__ y, const int* __restrict__ cluster_i,
                       float* __restrict__ Xn){
  int t = threadIdx.x;                  // 256 threads
  int node0 = blockIdx.x * 32;
  float acc = 0.0f;
  int cur = cluster_i[node0];
  for (int j = 0; j < 32; ++j){
    int node = node0 + j;
    int c = cluster_i[node];
    if (c != cur){
      atomicAdd(&Xn[(size_t)cur * N_FEAT + t], acc);
      acc = 0.0f; cur = c;
    }
    acc += y[(size_t)node * N_FEAT + t];
  }
  atomicAdd(&Xn[(size_t)cur * N_FEAT + t], acc);
}

// A_c[cs,cd] += 1 per directed non-self edge crossing clusters (diag zeroed by ref)
__global__ void k_ac(const int* __restrict__ ei, const int* __restrict__ cluster_i,
                     float* __restrict__ Ac){
  int k = blockIdx.x * blockDim.x + threadIdx.x;
  if (k >= N_DIR) return;
  int s, d; edge_sd(ei, k, s, d);
  if (s == d) return;
  int cs = cluster_i[s], cd = cluster_i[d];
  if (cs != cd) atomicAdd(&Ac[(size_t)cs * N_NODES + cd], 1.0f);
}

// ---------- launcher ----------

extern "C" void kernel_launch(void* const* d_in, const int* in_sizes, int n_in,
                              void* d_out, int out_size, void* d_ws, size_t ws_size,
                              hipStream_t stream){
  const float* x     = (const float*)d_in[0];
  const int*   ei    = (const int*)  d_in[1];
  const int*   batch = (const int*)  d_in[2];
  const float* lw    = (const float*)d_in[3];
  const float* lb    = (const float*)d_in[4];

  float* out = (float*)d_out;
  float* Xn  = out;                                       // 8192*256
  float* Ac  = Xn + (size_t)N_NODES * N_FEAT;             // 8192*8192
  float* ob  = Ac + (size_t)N_NODES * N_NODES;            // 8192 (new_batch)
  float* oc  = ob + N_NODES;                              // 8192 (cluster)

  char* w = (char*)d_ws;
  float* p1        = (float*)w; w += (size_t)N_NODES * 4;
  float* p2        = (float*)w; w += (size_t)N_NODES * 4;
  int*   cluster_i = (int*)  w; w += (size_t)N_NODES * 4;
  int*   Lg        = (int*)  w; w += (size_t)N_NODES * 4;
  // contiguous meta block: cnt | deg | np | ngact  (zeroed by k_start)
  int*   meta      = (int*)  w;
  int*   cnt       = meta;
  int*   deg       = meta + N_NODES;
  int*   np        = meta + 2 * N_NODES;
  int*   ngact     = meta + 2 * N_NODES + 1;
  int    nmeta     = 2 * N_NODES + 16;
  w += (size_t)nmeta * 4;
  unsigned int* pairs = (unsigned int*)w; w += (size_t)N_DIR * 4;
  unsigned int* gact  = (unsigned int*)w; w += (size_t)N_DIR * 4;
  uint2* edata     = (uint2*)w; w += (size_t)N_NODES * MAXDEG * 8;
  float* y         = (float*)w; w += (size_t)N_NODES * N_FEAT * 4;

  // Xn + Ac region (ob/oc handled by fused block 0)
  long long n4 = ((long long)N_NODES * N_FEAT + (long long)N_NODES * N_NODES) / 4;

  k_start  <<<(nmeta + 255) / 256, 256, 0, stream>>>(meta, nmeta, Lg);
  k_proj   <<<N_NODES, 256, 0, stream>>>(x, lw, p1, p2);
  k_edges  <<<N_DIR / 256, 256, 0, stream>>>(ei, p1, p2, lb, cnt, deg, edata, pairs, np);
  k_relax  <<<512, 256, 0, stream>>>(pairs, np, Lg);
  k_flat   <<<N_NODES / 256, 256, 0, stream>>>(Lg);
  k_relax  <<<512, 256, 0, stream>>>(pairs, np, Lg);
  k_flat   <<<N_NODES / 256, 256, 0, stream>>>(Lg);
  k_relax  <<<512, 256, 0, stream>>>(pairs, np, Lg);
  k_flat   <<<N_NODES / 256, 256, 0, stream>>>(Lg);
  k_collect<<<512, 256, 0, stream>>>(pairs, np, Lg, gact, ngact);
  k_fused  <<<256, 1024, 0, stream>>>(gact, ngact, Lg, batch, cluster_i, oc, ob,
                                      (u32x4*)out, n4);
  k_y      <<<N_NODES, 256, 0, stream>>>(x, edata, cnt, deg, y);
  k_xnew   <<<N_NODES / 32, 256, 0, stream>>>(y, cluster_i, Xn);
  k_ac     <<<N_DIR / 256, 256, 0, stream>>>(ei, cluster_i, Ac);
}